// Round 1
// baseline (6993.128 us; speedup 1.0000x reference)
//
#include <hip/hip_runtime.h>
#include <cstdint>
#include <cstddef>

#define NTAG 7

typedef unsigned int u32;
typedef unsigned long long u64;
using bf16x8 = __attribute__((ext_vector_type(8))) short;
using f32x4  = __attribute__((ext_vector_type(4))) float;

#define MFMA(A,B,C) __builtin_amdgcn_mfma_f32_16x16x32_bf16((A),(B),(C),0,0,0)

union abf { u64 q[2]; ushort e[8]; bf16x8 v; };

__device__ __forceinline__ u32 rtn_bf16(float f) {   // round-to-nearest-even
    u32 b = __float_as_uint(f);
    return (b + 0x7fffu + ((b >> 16) & 1u)) >> 16;
}

// ---------------------------------------------------------------------------
// Prep 1: fp32 -> bf16 (RTN) weight planes. order: 0=wif 1=whf 2=wib 3=whb
// ---------------------------------------------------------------------------
__global__ __launch_bounds__(256) void prep_w_kernel(
    const float* __restrict__ wif, const float* __restrict__ whf,
    const float* __restrict__ wib, const float* __restrict__ whb,
    ushort* __restrict__ planes)
{
    int f = blockIdx.x * 256 + threadIdx.x;          // x8 elems
    int mat = f >> 17;
    int i8 = (f & 0x1FFFF) << 3;
    const float* src = (mat == 0) ? wif : (mat == 1) ? whf : (mat == 2) ? wib : whb;
    float4 v0 = *(const float4*)(src + i8);
    float4 v1 = *(const float4*)(src + i8 + 4);
    ushort o[8];
    const float* pv = (const float*)&v0;
#pragma unroll
    for (int j = 0; j < 4; ++j) o[j] = (ushort)rtn_bf16(pv[j]);
    pv = (const float*)&v1;
#pragma unroll
    for (int j = 0; j < 4; ++j) o[4 + j] = (ushort)rtn_bf16(pv[j]);
    ushort* dst = planes + ((size_t)mat << 20) + i8;
    *(ushort4*)dst = make_ushort4(o[0], o[1], o[2], o[3]);
    *(ushort4*)(dst + 4) = make_ushort4(o[4], o[5], o[6], o[7]);
}

// ---------------------------------------------------------------------------
// Prep 2: xb[b][t][e] = bf16(emb[sent[b][t]][e])
// ---------------------------------------------------------------------------
__global__ __launch_bounds__(256) void prep_x_kernel(
    const int* __restrict__ sent, const float* __restrict__ emb,
    ushort* __restrict__ xb)
{
    long f = (long)blockIdx.x * 256 + threadIdx.x;   // x8 elems
    long e8 = f << 3;
    int bt = (int)(e8 >> 9);
    int e  = (int)(e8 & 511);
    int tok = sent[bt];
    const float* src = emb + (size_t)tok * 512 + e;
    float4 v0 = *(const float4*)(src);
    float4 v1 = *(const float4*)(src + 4);
    ushort o[8];
    const float* pv = (const float*)&v0;
#pragma unroll
    for (int j = 0; j < 4; ++j) o[j] = (ushort)rtn_bf16(pv[j]);
    pv = (const float*)&v1;
#pragma unroll
    for (int j = 0; j < 4; ++j) o[4 + j] = (ushort)rtn_bf16(pv[j]);
    ushort* dst = xb + e8;
    *(ushort4*)dst = make_ushort4(o[0], o[1], o[2], o[3]);
    *(ushort4*)(dst + 4) = make_ushort4(o[4], o[5], o[6], o[7]);
}

// ---------------------------------------------------------------------------
// Prep 3: gx[d][t][gu][b] = sum_e x[b][t][e] * W_ih_d[gu][e]   (f32)
// Bit-identical to the in-loop x_phase: same MFMA instruction, same kb
// even/odd accumulator chains, A/B roles swapped (k-ordered dot product
// is operand-role symmetric). 512 blocks: d(2) x gu-quarter(4) x t-chunk(64).
// Wave w owns gu tiles (w*8+i)*16 within its quarter; A (W rows) register-
// resident per tile; B (x) streamed from L2/L3.
// ---------------------------------------------------------------------------
__global__ __launch_bounds__(256, 1) void gates_kernel(
    const ushort* __restrict__ planes, const ushort* __restrict__ xb,
    float* __restrict__ gx)
{
    const int tid = threadIdx.x;
    const int w  = tid >> 6;
    const int L  = tid & 63;
    const int ln = L & 15;
    const int lk = L >> 4;
    const int d  = blockIdx.x & 1;
    const int gq = (blockIdx.x >> 1) & 3;
    const int tc = blockIdx.x >> 3;          // 0..63
    const int gu0 = gq << 9;
    const int t0  = tc << 3;

    const ushort* wip = planes + ((size_t)(d ? 2 : 0) << 20);
    float* gxd = gx + (size_t)d * (512ull * 2048 * 64);

#pragma unroll 1
    for (int i = 0; i < 8; ++i) {
        const int gub = gu0 + (w * 8 + i) * 16;
        bf16x8 Aw[16];
#pragma unroll
        for (int kb = 0; kb < 16; ++kb)
            Aw[kb] = *(const bf16x8*)(wip + (size_t)(gub + ln) * 512 + kb * 32 + lk * 8);
#pragma unroll 1
        for (int tt = 0; tt < 8; ++tt) {
            const int t = t0 + tt;
#pragma unroll 1
            for (int bt = 0; bt < 4; ++bt) {
                const ushort* xr = xb + ((size_t)(bt * 16 + ln) * 512 + t) * 512;
                f32x4 aa = {0,0,0,0}, ab = {0,0,0,0};
#pragma unroll
                for (int kb = 0; kb < 16; ++kb) {
                    bf16x8 Bx = *(const bf16x8*)(xr + kb * 32 + lk * 8);
                    if (kb & 1) ab = MFMA(Aw[kb], Bx, ab);
                    else        aa = MFMA(Aw[kb], Bx, aa);
                }
                f32x4 acc = aa + ab;
                float* dst = gxd + ((size_t)t * 2048 + gub + lk * 4) * 64 + bt * 16 + ln;
#pragma unroll
                for (int r = 0; r < 4; ++r)
                    __builtin_nontemporal_store(acc[r], dst + (size_t)r * 64);
            }
        }
    }
}

// ---------------------------------------------------------------------------
// Main persistent kernel: 128 blocks x 256 thr (4 waves), 1 block/CU.
// group g = blockIdx&7 = (dir d, batch-quarter bq: 16 batches); slot =
// blockIdx>>3 -> 32 units. wave w = gate w, 2 n-tiles of 16 units.
// W_hh bf16 B-frags register-resident. h exchanged as bf16 via relaxed
// agent atomics; 16-block flag barrier. With gx: x-partials are a pure
// prefetchable stream (2x float4/lane), issued in the barrier shadow;
// logits atomics issued AFTER the flag store so s_waitcnt(0) drains only
// the 4B h-store. h-phase loads batch-issued (A[16]) before the MFMA chain.
// ---------------------------------------------------------------------------
__global__ __launch_bounds__(256, 1) void lstm_mfma_kernel(
    const int* __restrict__ sent, const float* __restrict__ emb,
    const ushort* __restrict__ planes, const ushort* __restrict__ xb,
    const float* __restrict__ gx,
    const float* __restrict__ bif, const float* __restrict__ bhf,
    const float* __restrict__ bib, const float* __restrict__ bhb,
    const float* __restrict__ wout,
    const float* __restrict__ h0, const float* __restrict__ c0,
    ushort* __restrict__ hglob,   // [2 par][2 d][64 b][512] bf16
    float* __restrict__ logits,   // [512][64][7] atomicAdd
    int* __restrict__ flags)      // [8 g][16 slot][16 pad]
{
    __shared__ float sums_s[4 * 16 * 33];   // [gate][b][33]
    __shared__ float hv_s[16 * 33];
    __shared__ float bias_s[4 * 32];
    __shared__ float wout_s[7 * 33];

    const int tid = threadIdx.x;
    const int w   = tid >> 6;       // wave = gate
    const int L   = tid & 63;
    const int ln  = L & 15;
    const int lk  = L >> 4;
    const int g   = blockIdx.x & 7;
    const int slot= blockIdx.x >> 3;
    const int d   = g & 1;
    const int bq  = g >> 1;
    const int B0  = bq << 4;
    const int u0  = slot << 5;

    const ushort* wip = planes + ((size_t)(d ? 2 : 0) << 20);
    const ushort* whp = planes + ((size_t)(d ? 3 : 1) << 20);

    // register-resident W_hh B-frags: rows = gate w, units u0 + h*16 + ln
    bf16x8 Bh[2][16];
#pragma unroll
    for (int h = 0; h < 2; ++h) {
        const size_t row = (size_t)(w * 512 + u0 + h * 16 + ln);
#pragma unroll
        for (int kb = 0; kb < 16; ++kb)
            Bh[h][kb] = *(const bf16x8*)(whp + row * 512 + kb * 32 + lk * 8);
    }
    if (tid < 128) {
        int gg = tid >> 5, uu = tid & 31;
        int grow = gg * 512 + u0 + uu;
        bias_s[tid] = d ? (bib[grow] + bhb[grow]) : (bif[grow] + bhf[grow]);
    }
    if (tid < 224) {
        int tg = tid >> 5, uu = tid & 31;
        wout_s[tg * 33 + uu] = wout[(size_t)tg * 1024 + d * 512 + u0 + uu];
    }
    // c-state: thread -> (b = tid>>4, units uh*2, uh*2+1)
    const int cb = tid >> 4, uh = tid & 15;
    float cst[2];
    {
        const float* cr = c0 + ((size_t)(d * 64) + B0 + cb) * 512 + u0 + uh * 2;
        cst[0] = cr[0]; cst[1] = cr[1];
    }
    __syncthreads();

    const int gb = B0 + ln;                 // this lane's global batch
    f32x4 xacc0, xacc1;

    // gx stream bases (per-lane): [t][gu][b], gu = w*512+u0(+16)+ln, b = B0+lk*4
    const float* gxl0 = nullptr;
    const float* gxl1 = nullptr;
    if (gx) {
        const float* gxd = gx + (size_t)d * (512ull * 2048 * 64);
        gxl0 = gxd + ((size_t)(w * 512 + u0 + ln)) * 64 + B0 + lk * 4;
        gxl1 = gxd + ((size_t)(w * 512 + u0 + 16 + ln)) * 64 + B0 + lk * 4;
    }
    auto gx_fetch = [&](int t) {
        xacc0 = __builtin_nontemporal_load((const f32x4*)(gxl0 + (size_t)t * (2048 * 64)));
        xacc1 = __builtin_nontemporal_load((const f32x4*)(gxl1 + (size_t)t * (2048 * 64)));
    };

    // fallback x-phase (ws too small for gx): accumulates x_t . W_ih^T
    auto x_phase = [&](int tnext) {
        f32x4 a0a = {0,0,0,0}, a0b = {0,0,0,0}, a1a = {0,0,0,0}, a1b = {0,0,0,0};
        const size_t row0 = (size_t)(w * 512 + u0 + ln);
        const size_t row1 = row0 + 16;
#pragma unroll
        for (int kb = 0; kb < 16; ++kb) {
            bf16x8 A;
            if (xb) {
                A = *(const bf16x8*)(xb + ((size_t)gb * 512 + tnext) * 512 + kb * 32 + lk * 8);
            } else {
                int tok = sent[gb * 512 + tnext];
                const float* xr = emb + (size_t)tok * 512 + kb * 32 + lk * 8;
                float4 f0 = *(const float4*)(xr);
                float4 f1 = *(const float4*)(xr + 4);
                abf t;
                const float* pv = (const float*)&f0;
#pragma unroll
                for (int j = 0; j < 4; ++j) t.e[j] = (ushort)rtn_bf16(pv[j]);
                pv = (const float*)&f1;
#pragma unroll
                for (int j = 0; j < 4; ++j) t.e[4 + j] = (ushort)rtn_bf16(pv[j]);
                A = t.v;
            }
            bf16x8 Bx0 = *(const bf16x8*)(wip + row0 * 512 + kb * 32 + lk * 8);
            bf16x8 Bx1 = *(const bf16x8*)(wip + row1 * 512 + kb * 32 + lk * 8);
            if (kb & 1) { a0b = MFMA(A, Bx0, a0b); a1b = MFMA(A, Bx1, a1b); }
            else        { a0a = MFMA(A, Bx0, a0a); a1a = MFMA(A, Bx1, a1a); }
        }
        xacc0 = a0a + a0b;
        xacc1 = a1a + a1b;
    };

    if (gx) gx_fetch(d ? 511 : 0); else x_phase(d ? 511 : 0);

    for (int s = 0; s < 512; ++s) {
        const int t = d ? (511 - s) : s;

        // ---- wait for all 16 producer blocks of this group (flag array) ----
        if (s > 0 && w == 0) {
            const int* fp = flags + (((g << 4) + (L & 15)) << 4);
            while (true) {
                int v = __hip_atomic_load(fp, __ATOMIC_RELAXED, __HIP_MEMORY_SCOPE_AGENT);
                if (__all(v >= s)) break;
                __builtin_amdgcn_s_sleep(1);
            }
        }
        __syncthreads();

        // ---- h-phase MFMA onto x partials ----
        f32x4 f0a = xacc0, f0b = {0,0,0,0}, f1a = xacc1, f1b = {0,0,0,0};
        if (s == 0) {
            const float* hr = h0 + ((size_t)(d * 64) + gb) * 512;
#pragma unroll
            for (int kb = 0; kb < 16; ++kb) {
                float4 q0 = *(const float4*)(hr + kb * 32 + lk * 8);
                float4 q1 = *(const float4*)(hr + kb * 32 + lk * 8 + 4);
                abf A;
                const float* pv = (const float*)&q0;
#pragma unroll
                for (int j = 0; j < 4; ++j) A.e[j] = (ushort)rtn_bf16(pv[j]);
                pv = (const float*)&q1;
#pragma unroll
                for (int j = 0; j < 4; ++j) A.e[4 + j] = (ushort)rtn_bf16(pv[j]);
                if (kb & 1) { f0b = MFMA(A.v, Bh[0][kb], f0b); f1b = MFMA(A.v, Bh[1][kb], f1b); }
                else        { f0a = MFMA(A.v, Bh[0][kb], f0a); f1a = MFMA(A.v, Bh[1][kb], f1a); }
            }
        } else {
            const ushort* hbase = hglob + ((size_t)((s & 1) * 2 + d) * 64 + gb) * 512;
            abf A[16];                       // batch-issue all 32 exchange loads
#pragma unroll
            for (int kb = 0; kb < 16; ++kb) {
                const u64* hp = (const u64*)(hbase + kb * 32 + lk * 8);
                A[kb].q[0] = __hip_atomic_load(hp + 0, __ATOMIC_RELAXED, __HIP_MEMORY_SCOPE_AGENT);
                A[kb].q[1] = __hip_atomic_load(hp + 1, __ATOMIC_RELAXED, __HIP_MEMORY_SCOPE_AGENT);
            }
#pragma unroll
            for (int kb = 0; kb < 16; ++kb) {
                if (kb & 1) { f0b = MFMA(A[kb].v, Bh[0][kb], f0b); f1b = MFMA(A[kb].v, Bh[1][kb], f1b); }
                else        { f0a = MFMA(A[kb].v, Bh[0][kb], f0a); f1a = MFMA(A[kb].v, Bh[1][kb], f1a); }
            }
        }
        f32x4 g0 = f0a + f0b, g1 = f1a + f1b;

        // ---- gate sums -> LDS: C row = batch lk*4+r, col = unit ----
#pragma unroll
        for (int r = 0; r < 4; ++r) {
            int b = lk * 4 + r;
            sums_s[w * 528 + b * 33 + ln]      = g0[r];
            sums_s[w * 528 + b * 33 + 16 + ln] = g1[r];
        }
        __syncthreads();

        // ---- cell update: all 256 threads, 2 (b,u) pairs ----
        {
            u32 pk = 0;
#pragma unroll
            for (int e = 0; e < 2; ++e) {
                int u = uh * 2 + e;
                float si = sums_s[0 * 528 + cb * 33 + u] + bias_s[u];
                float sf = sums_s[1 * 528 + cb * 33 + u] + bias_s[32 + u];
                float sg = sums_s[2 * 528 + cb * 33 + u] + bias_s[64 + u];
                float so = sums_s[3 * 528 + cb * 33 + u] + bias_s[96 + u];
                float ig = 1.f / (1.f + expf(-si));
                float fg = 1.f / (1.f + expf(-sf));
                float gv = tanhf(sg);
                float og = 1.f / (1.f + expf(-so));
                float cn = fg * cst[e] + ig * gv;
                cst[e] = cn;
                float hh = og * tanhf(cn);
                hv_s[cb * 33 + u] = hh;
                pk |= rtn_bf16(hh) << (16 * e);
            }
            u32* dst = (u32*)(hglob + ((size_t)(((s + 1) & 1) * 2 + d) * 64 + B0 + cb) * 512 + u0 + uh * 2);
            __hip_atomic_store(dst, pk, __ATOMIC_RELAXED, __HIP_MEMORY_SCOPE_AGENT);
        }
        __syncthreads();

        // ---- drain h store ONLY, arrive (parallel flag store) ----
        __builtin_amdgcn_s_waitcnt(0);
        __syncthreads();
        if (tid == 0)
            __hip_atomic_store(flags + (((g << 4) + slot) << 4), s + 1,
                               __ATOMIC_RELAXED, __HIP_MEMORY_SCOPE_AGENT);

        // ---- next-step x partials: stream prefetch (or fallback compute) ----
        if (s < 511) {
            int tn = d ? (510 - s) : (s + 1);
            if (gx) gx_fetch(tn); else x_phase(tn);
        }

        // ---- partial tag logits (this block's 32 units), off critical path:
        //      atomics drain during next step's exchange, not before our flag.
        if (tid < 112) {
            int tg = tid >> 4, b = tid & 15;
            float a = 0.f;
#pragma unroll
            for (int u = 0; u < 32; ++u)
                a = fmaf(hv_s[b * 33 + u], wout_s[tg * 33 + u], a);
            atomicAdd(&logits[((size_t)t * 64 + B0 + b) * NTAG + tg], a);
        }
    }
}

// ---------------------------------------------------------------------------
// Viterbi decode: one wave per batch (lanes 0..6 = tags), byte backpointers.
// ---------------------------------------------------------------------------
__global__ __launch_bounds__(256) void viterbi_kernel(
    const float* __restrict__ logits, const float* __restrict__ bout,
    const float* __restrict__ trans,
    unsigned char* __restrict__ bp,   // [64][512][8]
    float* __restrict__ out)          // [64 scores][64*512 paths]
{
    __shared__ float Ls[4][512][7];
    const int tid = threadIdx.x;
    const int b0 = blockIdx.x << 2;

    for (int idx = tid; idx < 4 * 512 * 7; idx += 256) {
        int bl = idx / 3584;
        int rem = idx - bl * 3584;
        int t = rem / 7;
        int tg = rem - t * 7;
        Ls[bl][t][tg] = logits[((size_t)t * 64 + b0 + bl) * 7 + tg] + bout[tg];
    }
    __syncthreads();

    const int w = tid >> 6;
    const int lane = tid & 63;
    const int b = b0 + w;
    const int k = lane;

    float tr[7];
#pragma unroll
    for (int j = 0; j < 7; ++j) tr[j] = (k < 7) ? trans[j * 7 + k] : -1e30f;
    float prev = (k < 7) ? Ls[w][0][k] : -1e30f;
    unsigned char* bpb = bp + (size_t)b * 512 * 8;

    for (int t = 1; t < 512; ++t) {
        float best = __shfl(prev, 0, 64) + tr[0];
        int bj = 0;
#pragma unroll
        for (int j = 1; j < 7; ++j) {
            float v = __shfl(prev, j, 64) + tr[j];
            if (v > best) { best = v; bj = j; }   // strict > = first argmax
        }
        float lv = (k < 7) ? Ls[w][t][k] : 0.f;
        if (k < 7) bpb[t * 8 + k] = (unsigned char)bj;
        prev = lv + best;
    }

    float pv[7];
#pragma unroll
    for (int j = 0; j < 7; ++j) pv[j] = __shfl(prev, j, 64);
    float best = pv[0]; int bj = 0;
#pragma unroll
    for (int j = 1; j < 7; ++j) if (pv[j] > best) { best = pv[j]; bj = j; }
    if (lane == 0) {
        out[b] = best;
        out[64 + (size_t)b * 512 + 511] = (float)bj;
    }

    int cur = bj;
    for (int tc = 448; tc >= 0; tc -= 64) {
        int t = tc + lane;
        u64 row = *(const u64*)(bpb + (size_t)t * 8);
        for (int i = 63; i >= 0; --i) {
            int t2 = tc + i;
            if (t2 < 1) break;
            u64 r = __shfl(row, i, 64);
            cur = (int)((r >> (cur * 8)) & 0xFF);
            if (lane == 0) out[64 + (size_t)b * 512 + (t2 - 1)] = (float)cur;
        }
    }
}

// ---------------------------------------------------------------------------
extern "C" void kernel_launch(void* const* d_in, const int* in_sizes, int n_in,
                              void* d_out, int out_size, void* d_ws, size_t ws_size,
                              hipStream_t stream)
{
    (void)in_sizes; (void)n_in; (void)out_size;
    const int*   sent = (const int*)d_in[0];
    const float* emb  = (const float*)d_in[1];
    const float* wif  = (const float*)d_in[2];
    const float* whf  = (const float*)d_in[3];
    const float* bif  = (const float*)d_in[4];
    const float* bhf  = (const float*)d_in[5];
    const float* wib  = (const float*)d_in[6];
    const float* whb  = (const float*)d_in[7];
    const float* bib  = (const float*)d_in[8];
    const float* bhb  = (const float*)d_in[9];
    const float* wout = (const float*)d_in[10];
    const float* bout = (const float*)d_in[11];
    const float* h0   = (const float*)d_in[12];
    const float* c0   = (const float*)d_in[13];
    const float* trans= (const float*)d_in[14];
    float* out = (float*)d_out;

    // ws: logits(917504) | flags(8192) | hglob(262144) | bp(262144)
    //     | planes(8MB) | xb(32MB optional) | gx(512MB optional)
    char* p = (char*)d_ws;
    float*  logits = (float*)p;            p += 917504;
    int*    flags  = (int*)p;              p += 8192;
    ushort* hglob  = (ushort*)p;           p += 2 * 2 * 64 * 512 * 2;   // 262144
    unsigned char* bp = (unsigned char*)p; p += 262144;
    ushort* planes = (ushort*)p;           p += 4 * 1048576 * 2;        // 8 MB
    size_t base_need = (size_t)(p - (char*)d_ws);
    ushort* xb = nullptr;
    float*  gx = nullptr;
    if (ws_size >= base_need + (size_t)64 * 512 * 512 * 2) {
        xb = (ushort*)p;  p += (size_t)64 * 512 * 512 * 2;              // 32 MB
        if (ws_size >= (size_t)(p - (char*)d_ws) + 2ull * 512 * 2048 * 64 * 4)
            gx = (float*)p;                                             // 512 MB
    }

    hipMemsetAsync(d_ws, 0, 917504 + 8192, stream);   // logits + flags
    prep_w_kernel<<<2048, 256, 0, stream>>>(wif, whf, wib, whb, planes);
    if (xb) prep_x_kernel<<<8192, 256, 0, stream>>>(sent, emb, xb);
    if (gx) gates_kernel<<<512, 256, 0, stream>>>(planes, xb, gx);
    lstm_mfma_kernel<<<128, 256, 0, stream>>>(
        sent, emb, planes, xb, gx, bif, bhf, bib, bhb,
        wout, h0, c0, hglob, logits, flags);
    viterbi_kernel<<<16, 256, 0, stream>>>(logits, bout, trans, bp, out);
}

// Round 3
// 5612.327 us; speedup vs baseline: 1.2460x; 1.2460x over previous
//
#include <hip/hip_runtime.h>
#include <cstdint>
#include <cstddef>

#define NTAG 7

typedef unsigned int u32;
typedef unsigned long long u64;
using bf16x8 = __attribute__((ext_vector_type(8))) short;
using f32x4  = __attribute__((ext_vector_type(4))) float;

#define MFMA(A,B,C) __builtin_amdgcn_mfma_f32_16x16x32_bf16((A),(B),(C),0,0,0)

union abf { u64 q[2]; ushort e[8]; bf16x8 v; };

__device__ __forceinline__ u32 rtn_bf16(float f) {   // round-to-nearest-even
    u32 b = __float_as_uint(f);
    return (b + 0x7fffu + ((b >> 16) & 1u)) >> 16;
}

// ---------------------------------------------------------------------------
// Prep 1: fp32 -> bf16 (RTN) weight planes. order: 0=wif 1=whf 2=wib 3=whb
// ---------------------------------------------------------------------------
__global__ __launch_bounds__(256) void prep_w_kernel(
    const float* __restrict__ wif, const float* __restrict__ whf,
    const float* __restrict__ wib, const float* __restrict__ whb,
    ushort* __restrict__ planes)
{
    int f = blockIdx.x * 256 + threadIdx.x;          // x8 elems
    int mat = f >> 17;
    int i8 = (f & 0x1FFFF) << 3;
    const float* src = (mat == 0) ? wif : (mat == 1) ? whf : (mat == 2) ? wib : whb;
    float4 v0 = *(const float4*)(src + i8);
    float4 v1 = *(const float4*)(src + i8 + 4);
    ushort o[8];
    const float* pv = (const float*)&v0;
#pragma unroll
    for (int j = 0; j < 4; ++j) o[j] = (ushort)rtn_bf16(pv[j]);
    pv = (const float*)&v1;
#pragma unroll
    for (int j = 0; j < 4; ++j) o[4 + j] = (ushort)rtn_bf16(pv[j]);
    ushort* dst = planes + ((size_t)mat << 20) + i8;
    *(ushort4*)dst = make_ushort4(o[0], o[1], o[2], o[3]);
    *(ushort4*)(dst + 4) = make_ushort4(o[4], o[5], o[6], o[7]);
}

// ---------------------------------------------------------------------------
// Prep 2: xb[b][t][e] = bf16(emb[sent[b][t]][e])
// ---------------------------------------------------------------------------
__global__ __launch_bounds__(256) void prep_x_kernel(
    const int* __restrict__ sent, const float* __restrict__ emb,
    ushort* __restrict__ xb)
{
    long f = (long)blockIdx.x * 256 + threadIdx.x;   // x8 elems
    long e8 = f << 3;
    int bt = (int)(e8 >> 9);
    int e  = (int)(e8 & 511);
    int tok = sent[bt];
    const float* src = emb + (size_t)tok * 512 + e;
    float4 v0 = *(const float4*)(src);
    float4 v1 = *(const float4*)(src + 4);
    ushort o[8];
    const float* pv = (const float*)&v0;
#pragma unroll
    for (int j = 0; j < 4; ++j) o[j] = (ushort)rtn_bf16(pv[j]);
    pv = (const float*)&v1;
#pragma unroll
    for (int j = 0; j < 4; ++j) o[4 + j] = (ushort)rtn_bf16(pv[j]);
    ushort* dst = xb + e8;
    *(ushort4*)dst = make_ushort4(o[0], o[1], o[2], o[3]);
    *(ushort4*)(dst + 4) = make_ushort4(o[4], o[5], o[6], o[7]);
}

// ---------------------------------------------------------------------------
// Main persistent kernel: 128 blocks x 256 thr (4 waves), 1 block/CU.
// group g = blockIdx&7 = (dir d, batch-quarter bq: 16 batches); slot =
// blockIdx>>3 -> 32 units. wave w = gate w, 2 n-tiles of 16 units.
// Congestion-reduction (safe LDS budget ~32KB):
//  - per-group flags packed in ONE 64B line (poll = 1 MALL line req, was 16)
//  - h exchange staged once per block into LDS (co-op 64B/thread coalesced
//    agent loads, XOR-swizzled LDS, 2-way conflicts = free) ->
//    16KB/block/step MALL reads (was 64KB: 4x redundant per-wave loads)
//  - logits partials buffered in LDS, atomics flushed every 8 steps ->
//    pre-flag s_waitcnt(0) stops draining contended RMWs 7/8 steps
// ---------------------------------------------------------------------------
__global__ __launch_bounds__(256, 1) void lstm_mfma_kernel(
    const int* __restrict__ sent, const float* __restrict__ emb,
    const ushort* __restrict__ planes, const ushort* __restrict__ xb,
    const float* __restrict__ bif, const float* __restrict__ bhf,
    const float* __restrict__ bib, const float* __restrict__ bhb,
    const float* __restrict__ wout,
    const float* __restrict__ h0, const float* __restrict__ c0,
    ushort* __restrict__ hglob,   // [2 par][2 d][64 b][512] bf16
    float* __restrict__ logits,   // [512][64][7] atomicAdd
    int* __restrict__ flags)      // [8 g][16 slot]  (one 64B line per group)
{
    __shared__ __align__(16) ushort hstage[16 * 512];   // 16384 B, XOR-swz rows
    __shared__ float sums_s[4 * 16 * 33];               //  8448 B
    __shared__ float hv_s[16 * 33];                     //  2112 B
    __shared__ float bias_s[4 * 32];                    //   512 B
    __shared__ float wout_s[7 * 33];                    //   924 B
    __shared__ float lbuf[8 * 112];                     //  3584 B

    const int tid = threadIdx.x;
    const int w   = tid >> 6;       // wave = gate
    const int L   = tid & 63;
    const int ln  = L & 15;
    const int lk  = L >> 4;
    const int g   = blockIdx.x & 7;
    const int slot= blockIdx.x >> 3;
    const int d   = g & 1;
    const int bq  = g >> 1;
    const int B0  = bq << 4;
    const int u0  = slot << 5;

    const ushort* wip = planes + ((size_t)(d ? 2 : 0) << 20);
    const ushort* whp = planes + ((size_t)(d ? 3 : 1) << 20);

    // register-resident W_hh B-frags: rows = gate w, units u0 + h*16 + ln
    bf16x8 Bh[2][16];
#pragma unroll
    for (int h = 0; h < 2; ++h) {
        const size_t row = (size_t)(w * 512 + u0 + h * 16 + ln);
#pragma unroll
        for (int kb = 0; kb < 16; ++kb)
            Bh[h][kb] = *(const bf16x8*)(whp + row * 512 + kb * 32 + lk * 8);
    }
    if (tid < 128) {
        int gg = tid >> 5, uu = tid & 31;
        int grow = gg * 512 + u0 + uu;
        bias_s[tid] = d ? (bib[grow] + bhb[grow]) : (bif[grow] + bhf[grow]);
    }
    if (tid < 224) {
        int tg = tid >> 5, uu = tid & 31;
        wout_s[tg * 33 + uu] = wout[(size_t)tg * 1024 + d * 512 + u0 + uu];
    }
    // c-state: thread -> (b = tid>>4, units uh*2, uh*2+1)
    const int cb = tid >> 4, uh = tid & 15;
    float cst[2];
    {
        const float* cr = c0 + ((size_t)(d * 64) + B0 + cb) * 512 + u0 + uh * 2;
        cst[0] = cr[0]; cst[1] = cr[1];
    }
    __syncthreads();

    const int gb = B0 + ln;                 // this lane's global batch
    f32x4 xacc0, xacc1;

    // x-phase: accumulates x_t . W_ih^T (B-frags streamed from L2)
    auto x_phase = [&](int tnext) {
        f32x4 a0a = {0,0,0,0}, a0b = {0,0,0,0}, a1a = {0,0,0,0}, a1b = {0,0,0,0};
        const size_t row0 = (size_t)(w * 512 + u0 + ln);
        const size_t row1 = row0 + 16;
#pragma unroll
        for (int kb = 0; kb < 16; ++kb) {
            bf16x8 A;
            if (xb) {
                A = *(const bf16x8*)(xb + ((size_t)gb * 512 + tnext) * 512 + kb * 32 + lk * 8);
            } else {
                int tok = sent[gb * 512 + tnext];
                const float* xr = emb + (size_t)tok * 512 + kb * 32 + lk * 8;
                float4 f0 = *(const float4*)(xr);
                float4 f1 = *(const float4*)(xr + 4);
                abf t;
                const float* pv = (const float*)&f0;
#pragma unroll
                for (int j = 0; j < 4; ++j) t.e[j] = (ushort)rtn_bf16(pv[j]);
                pv = (const float*)&f1;
#pragma unroll
                for (int j = 0; j < 4; ++j) t.e[4 + j] = (ushort)rtn_bf16(pv[j]);
                A = t.v;
            }
            bf16x8 Bx0 = *(const bf16x8*)(wip + row0 * 512 + kb * 32 + lk * 8);
            bf16x8 Bx1 = *(const bf16x8*)(wip + row1 * 512 + kb * 32 + lk * 8);
            if (kb & 1) { a0b = MFMA(A, Bx0, a0b); a1b = MFMA(A, Bx1, a1b); }
            else        { a0a = MFMA(A, Bx0, a0a); a1a = MFMA(A, Bx1, a1a); }
        }
        xacc0 = a0a + a0b;
        xacc1 = a1a + a1b;
    };

    x_phase(d ? 511 : 0);

    const char* hsb = (const char*)hstage;
    const int hx = (ln & 7) << 4;           // read-side row swizzle

    for (int s = 0; s < 512; ++s) {
        const int t = d ? (511 - s) : s;

        // ---- wait for all 16 producer blocks: ONE packed 64B flag line ----
        if (s > 0 && w == 0) {
            const int* fp = flags + (g << 4) + (L & 15);
            while (true) {
                int v = __hip_atomic_load(fp, __ATOMIC_RELAXED, __HIP_MEMORY_SCOPE_AGENT);
                if (__all(v >= s)) break;
                __builtin_amdgcn_s_sleep(1);
            }
        }
        __syncthreads();

        // ---- h-phase MFMA onto x partials ----
        f32x4 f0a = xacc0, f0b = {0,0,0,0}, f1a = xacc1, f1b = {0,0,0,0};
        if (s == 0) {
            const float* hr = h0 + ((size_t)(d * 64) + gb) * 512;
#pragma unroll
            for (int kb = 0; kb < 16; ++kb) {
                float4 q0 = *(const float4*)(hr + kb * 32 + lk * 8);
                float4 q1 = *(const float4*)(hr + kb * 32 + lk * 8 + 4);
                abf A;
                const float* pv = (const float*)&q0;
#pragma unroll
                for (int j = 0; j < 4; ++j) A.e[j] = (ushort)rtn_bf16(pv[j]);
                pv = (const float*)&q1;
#pragma unroll
                for (int j = 0; j < 4; ++j) A.e[4 + j] = (ushort)rtn_bf16(pv[j]);
                if (kb & 1) { f0b = MFMA(A.v, Bh[0][kb], f0b); f1b = MFMA(A.v, Bh[1][kb], f1b); }
                else        { f0a = MFMA(A.v, Bh[0][kb], f0a); f1a = MFMA(A.v, Bh[1][kb], f1a); }
            }
        } else {
            // co-op stage: 16KB h tile, 64B/thread, coalesced agent loads.
            // thread -> row r = tid&15 (batch), 64B chunk base (tid>>4)*64;
            // LDS write addr XOR-swizzled by (r&7)<<4 (2-way = free)
            {
                const u64* hq = (const u64*)(hglob + ((size_t)((s & 1) * 2 + d) * 64 + B0) * 512);
                const int r = tid & 15, cq = tid >> 4;
                u64 tmp[8];
#pragma unroll
                for (int i = 0; i < 8; ++i)
                    tmp[i] = __hip_atomic_load(hq + r * 128 + cq * 8 + i,
                                               __ATOMIC_RELAXED, __HIP_MEMORY_SCOPE_AGENT);
                char* hd = (char*)hstage + r * 1024;
                const int rsw = (r & 7) << 4, c64 = cq * 64;
#pragma unroll
                for (int i = 0; i < 8; ++i)
                    *(u64*)(hd + ((c64 + (i >> 1) * 16) ^ rsw) + (i & 1) * 8) = tmp[i];
            }
            __syncthreads();
            abf A[16];
#pragma unroll
            for (int kb = 0; kb < 16; ++kb)
                A[kb].v = *(const bf16x8*)(hsb + ln * 1024 + ((kb * 64 + lk * 16) ^ hx));
#pragma unroll
            for (int kb = 0; kb < 16; ++kb) {
                if (kb & 1) { f0b = MFMA(A[kb].v, Bh[0][kb], f0b); f1b = MFMA(A[kb].v, Bh[1][kb], f1b); }
                else        { f0a = MFMA(A[kb].v, Bh[0][kb], f0a); f1a = MFMA(A[kb].v, Bh[1][kb], f1a); }
            }
        }
        f32x4 g0 = f0a + f0b, g1 = f1a + f1b;

        // ---- gate sums -> LDS: C row = batch lk*4+r, col = unit ----
#pragma unroll
        for (int r = 0; r < 4; ++r) {
            int b = lk * 4 + r;
            sums_s[w * 528 + b * 33 + ln]      = g0[r];
            sums_s[w * 528 + b * 33 + 16 + ln] = g1[r];
        }
        __syncthreads();

        // ---- cell update: all 256 threads, 2 (b,u) pairs ----
        {
            u32 pk = 0;
#pragma unroll
            for (int e = 0; e < 2; ++e) {
                int u = uh * 2 + e;
                float si = sums_s[0 * 528 + cb * 33 + u] + bias_s[u];
                float sf = sums_s[1 * 528 + cb * 33 + u] + bias_s[32 + u];
                float sg = sums_s[2 * 528 + cb * 33 + u] + bias_s[64 + u];
                float so = sums_s[3 * 528 + cb * 33 + u] + bias_s[96 + u];
                float ig = 1.f / (1.f + expf(-si));
                float fg = 1.f / (1.f + expf(-sf));
                float gv = tanhf(sg);
                float og = 1.f / (1.f + expf(-so));
                float cn = fg * cst[e] + ig * gv;
                cst[e] = cn;
                float hh = og * tanhf(cn);
                hv_s[cb * 33 + u] = hh;
                pk |= rtn_bf16(hh) << (16 * e);
            }
            u32* dst = (u32*)(hglob + ((size_t)(((s + 1) & 1) * 2 + d) * 64 + B0 + cb) * 512 + u0 + uh * 2);
            __hip_atomic_store(dst, pk, __ATOMIC_RELAXED, __HIP_MEMORY_SCOPE_AGENT);
        }
        __syncthreads();

        // ---- drain h store, arrive (parallel flag store into packed line) ----
        __builtin_amdgcn_s_waitcnt(0);
        __syncthreads();
        if (tid == 0)
            __hip_atomic_store(flags + (g << 4) + slot, s + 1,
                               __ATOMIC_RELAXED, __HIP_MEMORY_SCOPE_AGENT);

        // ---- next-step x partials in the barrier shadow ----
        if (s < 511) x_phase(d ? (510 - s) : (s + 1));

        // ---- tag-logit partials -> LDS buffer; flush atomics every 8 steps ----
        if (tid >= 144) {
            int q = tid - 144, tg = q >> 4, b = q & 15;
            float a = 0.f;
#pragma unroll
            for (int u = 0; u < 32; ++u)
                a = fmaf(hv_s[b * 33 + u], wout_s[tg * 33 + u], a);
            lbuf[(s & 7) * 112 + q] = a;
            if ((s & 7) == 7) {
#pragma unroll
                for (int k = 0; k < 8; ++k) {
                    int sk = s - 7 + k;
                    int tk = d ? (511 - sk) : sk;
                    atomicAdd(&logits[((size_t)tk * 64 + B0 + b) * NTAG + tg],
                              lbuf[k * 112 + q]);
                }
            }
        }
    }
}

// ---------------------------------------------------------------------------
// Viterbi decode: one wave per batch (lanes 0..6 = tags), byte backpointers.
// ---------------------------------------------------------------------------
__global__ __launch_bounds__(256) void viterbi_kernel(
    const float* __restrict__ logits, const float* __restrict__ bout,
    const float* __restrict__ trans,
    unsigned char* __restrict__ bp,   // [64][512][8]
    float* __restrict__ out)          // [64 scores][64*512 paths]
{
    __shared__ float Ls[4][512][7];
    const int tid = threadIdx.x;
    const int b0 = blockIdx.x << 2;

    for (int idx = tid; idx < 4 * 512 * 7; idx += 256) {
        int bl = idx / 3584;
        int rem = idx - bl * 3584;
        int t = rem / 7;
        int tg = rem - t * 7;
        Ls[bl][t][tg] = logits[((size_t)t * 64 + b0 + bl) * 7 + tg] + bout[tg];
    }
    __syncthreads();

    const int w = tid >> 6;
    const int lane = tid & 63;
    const int b = b0 + w;
    const int k = lane;

    float tr[7];
#pragma unroll
    for (int j = 0; j < 7; ++j) tr[j] = (k < 7) ? trans[j * 7 + k] : -1e30f;
    float prev = (k < 7) ? Ls[w][0][k] : -1e30f;
    unsigned char* bpb = bp + (size_t)b * 512 * 8;

    for (int t = 1; t < 512; ++t) {
        float best = __shfl(prev, 0, 64) + tr[0];
        int bj = 0;
#pragma unroll
        for (int j = 1; j < 7; ++j) {
            float v = __shfl(prev, j, 64) + tr[j];
            if (v > best) { best = v; bj = j; }   // strict > = first argmax
        }
        float lv = (k < 7) ? Ls[w][t][k] : 0.f;
        if (k < 7) bpb[t * 8 + k] = (unsigned char)bj;
        prev = lv + best;
    }

    float pv[7];
#pragma unroll
    for (int j = 0; j < 7; ++j) pv[j] = __shfl(prev, j, 64);
    float best = pv[0]; int bj = 0;
#pragma unroll
    for (int j = 1; j < 7; ++j) if (pv[j] > best) { best = pv[j]; bj = j; }
    if (lane == 0) {
        out[b] = best;
        out[64 + (size_t)b * 512 + 511] = (float)bj;
    }

    int cur = bj;
    for (int tc = 448; tc >= 0; tc -= 64) {
        int t = tc + lane;
        u64 row = *(const u64*)(bpb + (size_t)t * 8);
        for (int i = 63; i >= 0; --i) {
            int t2 = tc + i;
            if (t2 < 1) break;
            u64 r = __shfl(row, i, 64);
            cur = (int)((r >> (cur * 8)) & 0xFF);
            if (lane == 0) out[64 + (size_t)b * 512 + (t2 - 1)] = (float)cur;
        }
    }
}

// ---------------------------------------------------------------------------
extern "C" void kernel_launch(void* const* d_in, const int* in_sizes, int n_in,
                              void* d_out, int out_size, void* d_ws, size_t ws_size,
                              hipStream_t stream)
{
    (void)in_sizes; (void)n_in; (void)out_size;
    const int*   sent = (const int*)d_in[0];
    const float* emb  = (const float*)d_in[1];
    const float* wif  = (const float*)d_in[2];
    const float* whf  = (const float*)d_in[3];
    const float* bif  = (const float*)d_in[4];
    const float* bhf  = (const float*)d_in[5];
    const float* wib  = (const float*)d_in[6];
    const float* whb  = (const float*)d_in[7];
    const float* bib  = (const float*)d_in[8];
    const float* bhb  = (const float*)d_in[9];
    const float* wout = (const float*)d_in[10];
    const float* bout = (const float*)d_in[11];
    const float* h0   = (const float*)d_in[12];
    const float* c0   = (const float*)d_in[13];
    const float* trans= (const float*)d_in[14];
    float* out = (float*)d_out;

    // ws: logits(917504) | flags(8192 reserved, 512 used) | hglob(262144)
    //     | bp(262144) | planes(8MB) | xb(32MB optional)
    char* p = (char*)d_ws;
    float*  logits = (float*)p;            p += 917504;
    int*    flags  = (int*)p;              p += 8192;
    ushort* hglob  = (ushort*)p;           p += 2 * 2 * 64 * 512 * 2;   // 262144
    unsigned char* bp = (unsigned char*)p; p += 262144;
    ushort* planes = (ushort*)p;           p += 4 * 1048576 * 2;        // 8 MB
    size_t base_need = (size_t)(p - (char*)d_ws);
    ushort* xb = nullptr;
    if (ws_size >= base_need + (size_t)64 * 512 * 512 * 2) xb = (ushort*)p;

    hipMemsetAsync(d_ws, 0, 917504 + 8192, stream);   // logits + flags
    prep_w_kernel<<<2048, 256, 0, stream>>>(wif, whf, wib, whb, planes);
    if (xb) prep_x_kernel<<<8192, 256, 0, stream>>>(sent, emb, xb);
    lstm_mfma_kernel<<<128, 256, 0, stream>>>(
        sent, emb, planes, xb, bif, bhf, bib, bhb,
        wout, h0, c0, hglob, logits, flags);
    viterbi_kernel<<<16, 256, 0, stream>>>(logits, bout, trans, bp, out);
}